// Round 5
// baseline (181.647 us; speedup 1.0000x reference)
//
#include <hip/hip_runtime.h>
#include <climits>

// BoundingBox: mask [128,1,512,512] fp32 -> bbox [128,4] int32 (ymin,xmin,ymax+1,xmax+1)
// THRESH = 0.5; no hit anywhere -> (0,0,H,W).
//
// Single fused kernel, ZERO fences (R1 showed per-block __threadfence = 149us
// even cache-warm; this version replaces fences with data-dependency ordering
// on atomicMax return values). Mins encoded as (511-v) so all four reductions
// are atomicMax with one 0xFF memset init; per-image countdown counter starts
// at -1 (0xFF) so the same memset covers it. Last block per image reads the
// four cells via no-op atomicMax(e, INT_MIN) (coherent read) and writes out.

#define THRESH 0.5f

static constexpr int N = 128;
static constexpr int H = 512;
static constexpr int W = 512;
static constexpr int G = 32;         // row-groups per image -> 4096 blocks = 16/CU
static constexpr int ROWS = H / G;   // 16 rows per block
static constexpr int BLK = 256;      // 4 waves
static constexpr int W4 = W / 4;     // 128 float4 per row
static constexpr int ITER = ROWS * W4 / BLK;  // 8 float4 per thread

typedef float f32x4 __attribute__((ext_vector_type(4)));

__global__ __launch_bounds__(BLK)
void bbox_fused(const float* __restrict__ mask, int* __restrict__ enc,
                int* __restrict__ cnt, int* __restrict__ out) {
    const int n = blockIdx.x;   // image
    const int g = blockIdx.y;   // row group
    const f32x4* base =
        (const f32x4*)(mask + (size_t)n * H * W + (size_t)g * ROWS * W);

    const int c  = threadIdx.x & (W4 - 1);   // fixed column group 0..127
    const int rb = threadIdx.x >> 7;         // row parity 0..1

    // Issue ALL loads up front — 8 independent global_load_dwordx4 nt in flight.
    f32x4 v[ITER];
    #pragma unroll
    for (int k = 0; k < ITER; ++k)
        v[k] = __builtin_nontemporal_load(&base[threadIdx.x + k * BLK]);

    int ymin = INT_MAX, ymax = -1;
    float m0 = 0.f, m1 = 0.f, m2 = 0.f, m3 = 0.f;  // per-column max accumulators

    #pragma unroll
    for (int k = 0; k < ITER; ++k) {
        float mx = fmaxf(fmaxf(v[k].x, v[k].y), fmaxf(v[k].z, v[k].w));
        int r = 2 * k + rb;  // row of v[k] within this block's group
        if (mx >= THRESH) { ymin = min(ymin, r); ymax = max(ymax, r); }
        m0 = fmaxf(m0, v[k].x); m1 = fmaxf(m1, v[k].y);
        m2 = fmaxf(m2, v[k].z); m3 = fmaxf(m3, v[k].w);
    }

    // Block-local rows -> global rows.
    if (ymax >= 0) { ymin += g * ROWS; ymax += g * ROWS; }

    // x extent from accumulated column maxima (once, outside the loop).
    const int w = c << 2;
    int xmin = INT_MAX, xmax = -1;
    if (m0 >= THRESH) { xmin = w;                xmax = w;                }
    if (m1 >= THRESH) { xmin = min(xmin, w + 1); xmax = max(xmax, w + 1); }
    if (m2 >= THRESH) { xmin = min(xmin, w + 2); xmax = max(xmax, w + 2); }
    if (m3 >= THRESH) { xmin = min(xmin, w + 3); xmax = max(xmax, w + 3); }

    // Wave (64-lane) shuffle reduction.
    #pragma unroll
    for (int off = 32; off > 0; off >>= 1) {
        ymin = min(ymin, __shfl_down(ymin, off, 64));
        ymax = max(ymax, __shfl_down(ymax, off, 64));
        xmin = min(xmin, __shfl_down(xmin, off, 64));
        xmax = max(xmax, __shfl_down(xmax, off, 64));
    }

    __shared__ int s[BLK / 64][4];
    const int wave = threadIdx.x >> 6;
    const int lane = threadIdx.x & 63;
    if (lane == 0) {
        s[wave][0] = ymin; s[wave][1] = ymax; s[wave][2] = xmin; s[wave][3] = xmax;
    }
    __syncthreads();

    if (threadIdx.x == 0) {
        int a = s[0][0], b = s[0][1], cc = s[0][2], d = s[0][3];
        #pragma unroll
        for (int wv = 1; wv < BLK / 64; ++wv) {
            a  = min(a,  s[wv][0]); b = max(b, s[wv][1]);
            cc = min(cc, s[wv][2]); d = max(d, s[wv][3]);
        }
        // Encode so every reduction is a max; no-hit contributes -1 (== init).
        const bool hit = (b >= 0);
        const int va = hit ? (H - 1) - a  : -1;   // encoded ymin
        const int vb = hit ? b            : -1;   // ymax
        const int vc = hit ? (W - 1) - cc : -1;   // encoded xmin
        const int vd = hit ? d            : -1;   // xmax

        int* e = enc + (n << 2);
        int d0 = atomicMax(&e[0], va);
        int d1 = atomicMax(&e[1], vb);
        int d2 = atomicMax(&e[2], vc);
        int d3 = atomicMax(&e[3], vd);
        // Consume the return values: forces vmcnt drain (atomics complete at
        // the coherence point) before the counter add issues. No cache fence.
        int dep = d0 ^ d1 ^ d2 ^ d3;
        asm volatile("" : "+v"(dep) :: "memory");

        int old = atomicAdd(&cnt[n], 1);   // countdown from -1 (0xFF init)
        if (old == G - 2) {
            // Last block for this image: every other block's enc atomics
            // completed before its counter add was visible.
            int e0 = atomicMax(&e[0], INT_MIN);   // coherent read, never modifies
            int e1 = atomicMax(&e[1], INT_MIN);
            int e2 = atomicMax(&e[2], INT_MIN);
            int e3 = atomicMax(&e[3], INT_MIN);
            int4 r;
            if (e1 < 0) r = make_int4(0, 0, H, W);
            else        r = make_int4((H - 1) - e0, (W - 1) - e2, e1 + 1, e3 + 1);
            ((int4*)out)[n] = r;
        }
    }
}

extern "C" void kernel_launch(void* const* d_in, const int* in_sizes, int n_in,
                              void* d_out, int out_size, void* d_ws, size_t ws_size,
                              hipStream_t stream) {
    const float* mask = (const float*)d_in[0];
    int* enc = (int*)d_ws;          // N*4 ints, init -1 via 0xFF
    int* cnt = enc + N * 4;         // N ints, init -1 via the same fill
    int* out = (int*)d_out;

    hipMemsetAsync(d_ws, 0xFF, (size_t)(N * 5) * sizeof(int), stream);

    dim3 grid(N, G);
    bbox_fused<<<grid, BLK, 0, stream>>>(mask, enc, cnt, out);
}